// Round 2
// baseline (1411.372 us; speedup 1.0000x reference)
//
#include <hip/hip_runtime.h>
#include <cstddef>

// Problem constants (from reference)
#define BATCH 128
#define DIN   2048
#define NN    2048
#define TT    50
#define MM    (BATCH * TT)   // 6400, m = b*50 + t
#define BN_EPS 1e-4

// ---------------------------------------------------------------------------
// GEMM with fp64 accumulation: PSP[m][n] = sum_d X[b,d,t] * W[n,d], m = b*50+t
// fp32 staging in LDS, convert to double in registers, v_fma_f64 accumulate.
// 64x64 tile, BK=16, 256 threads, 4x4 doubles per thread.
// Rationale: spikes are a hard Heaviside at v>1.0; only an (essentially) exact
// PSP keeps every threshold crossing in agreement with the reference.
// ---------------------------------------------------------------------------
template <typename PT>
__global__ __launch_bounds__(256) void gemm_psp_kernel(
    const float* __restrict__ X,     // [B][DIN][T]
    const float* __restrict__ W,     // [N][DIN]
    PT* __restrict__ PSP)            // [M][N]
{
    __shared__ float As[16][64];
    __shared__ float Bs[16][68];     // +4 pad staggers banks

    const int tid = threadIdx.x;
    const int m0 = blockIdx.y * 64;  // 100 blocks
    const int n0 = blockIdx.x * 64;  // 32 blocks

    // A staging: lane over m (runs of 50 contiguous t), 4 k-rows per thread
    const int a_m = tid & 63;
    const int a_k = tid >> 6;                 // 0..3
    const int m_g = m0 + a_m;
    const int ab  = m_g / TT;
    const int at  = m_g - ab * TT;
    const float* Aptr = X + (size_t)ab * (DIN * TT) + at;   // + k*TT

    // B staging: float4 along k of W[N][K]
    const int b_n = tid >> 2;                 // 0..63
    const int b_k = (tid & 3) * 4;            // 0,4,8,12
    const float* Wptr = W + (size_t)(n0 + b_n) * DIN + b_k;

    const int ty = tid >> 4;   // 0..15 (m)
    const int tx = tid & 15;   // 0..15 (n)

    double acc[4][4];
#pragma unroll
    for (int i = 0; i < 4; ++i)
#pragma unroll
        for (int j = 0; j < 4; ++j) acc[i][j] = 0.0;

    for (int k0 = 0; k0 < DIN; k0 += 16) {
#pragma unroll
        for (int j = 0; j < 4; ++j) {
            const int kk = a_k + 4 * j;
            As[kk][a_m] = Aptr[(k0 + kk) * TT];
        }
        float4 w4 = *(const float4*)(Wptr + k0);
        Bs[b_k + 0][b_n] = w4.x;
        Bs[b_k + 1][b_n] = w4.y;
        Bs[b_k + 2][b_n] = w4.z;
        Bs[b_k + 3][b_n] = w4.w;
        __syncthreads();

#pragma unroll
        for (int k = 0; k < 16; ++k) {
            float4 a4 = *(const float4*)&As[k][ty * 4];
            float4 b4 = *(const float4*)&Bs[k][tx * 4];
            double ad[4] = {(double)a4.x, (double)a4.y, (double)a4.z, (double)a4.w};
            double bd[4] = {(double)b4.x, (double)b4.y, (double)b4.z, (double)b4.w};
#pragma unroll
            for (int i = 0; i < 4; ++i)
#pragma unroll
                for (int j = 0; j < 4; ++j)
                    acc[i][j] = fma(ad[i], bd[j], acc[i][j]);
        }
        __syncthreads();
    }

#pragma unroll
    for (int i = 0; i < 4; ++i) {
        const int m = m0 + ty * 4 + i;
        PT* row = PSP + (size_t)m * NN + n0 + tx * 4;
#pragma unroll
        for (int j = 0; j < 4; ++j) row[j] = (PT)acc[i][j];
    }
}

// ---------------------------------------------------------------------------
// BN stats per (t,n): two-pass mean / inv-std over batch, all fp64.
// ---------------------------------------------------------------------------
template <typename PT>
__global__ __launch_bounds__(256) void stats_kernel(
    const PT* __restrict__ PSP,       // [M][N], m=b*50+t
    const float* __restrict__ bias,   // [N]
    double* __restrict__ mean_out,    // [T][N]
    double* __restrict__ invstd_out)  // [T][N]
{
    const int t = blockIdx.x >> 3;
    const int n = ((blockIdx.x & 7) << 8) + threadIdx.x;
    const double bb = (double)bias[n];
    const PT* p = PSP + (size_t)t * NN + n;     // + b*(50*2048)

    double s = 0.0;
#pragma unroll 8
    for (int b = 0; b < BATCH; ++b) s += (double)p[(size_t)b * (TT * NN)];
    const double mean = s * (1.0 / BATCH) + bb;

    double ss = 0.0;
#pragma unroll 8
    for (int b = 0; b < BATCH; ++b) {
        double d = ((double)p[(size_t)b * (TT * NN)] + bb) - mean;
        ss += d * d;
    }
    const double var = ss * (1.0 / BATCH);
    mean_out[t * NN + n]   = mean;
    invstd_out[t * NN + n] = 1.0 / sqrt(var + BN_EPS);
}

// ---------------------------------------------------------------------------
// LIF recurrence (fp64 state) + coalesced spike writeout via LDS transpose.
// ---------------------------------------------------------------------------
template <typename PT>
__global__ __launch_bounds__(256) void recur_kernel(
    const PT* __restrict__ PSP,           // [M][N]
    const float* __restrict__ bias,       // [N]
    const double* __restrict__ mean_arr,  // [T][N]
    const double* __restrict__ invstd_arr,// [T][N]
    const float* __restrict__ gamma,      // [T][N]
    const float* __restrict__ decay_v,    // [N]
    const float* __restrict__ reset_decay,// [N]
    const float* __restrict__ reset_v,    // [N]
    float* __restrict__ out)              // spikes [B][N][T] ++ final_v ++ final_reset
{
    __shared__ float spk[256 * (TT + 1)];

    const int b  = blockIdx.x >> 3;
    const int nc = blockIdx.x & 7;
    const int n  = (nc << 8) + threadIdx.x;
    const int tid = threadIdx.x;

    const double dv = (double)decay_v[n];
    const double rd = (double)reset_decay[n];
    const double rv = (double)reset_v[n];
    const double bb = (double)bias[n];

    double v = 0.0, r = 0.0;
    const PT* p = PSP + (size_t)b * (TT * NN) + n;   // + t*NN
    const float* ga = gamma + n;
    const double* me = mean_arr + n;
    const double* is = invstd_arr + n;

    for (int t = 0; t < TT; ++t) {
        const double psp = (double)p[t * NN] + bb;
        const double bn  = (double)ga[t * NN] * (psp - me[t * NN]) * is[t * NN];
        v = v * dv + bn - r;
        const double s = (v > 1.0) ? 1.0 : 0.0;
        r = r * rd + s * rv;
        spk[tid * (TT + 1) + t] = (float)s;
    }
    __syncthreads();

    const size_t base = (size_t)b * (NN * TT) + (size_t)nc * (256 * TT);
    for (int i = tid; i < 256 * TT; i += 256) {
        const int n_l = i / TT;
        const int t   = i - n_l * TT;
        out[base + i] = spk[n_l * (TT + 1) + t];
    }

    const size_t fin = (size_t)BATCH * NN * TT;
    out[fin + (size_t)b * NN + n]                      = (float)v;
    out[fin + (size_t)BATCH * NN + (size_t)b * NN + n] = (float)r;
}

// ---------------------------------------------------------------------------
template <typename PT>
static void launch_all(const float* X, const float* W, const float* bias,
                       const float* gamma, const float* decay_v,
                       const float* reset_dec, const float* reset_v,
                       float* out, void* d_ws, hipStream_t stream)
{
    PT* PSP = (PT*)d_ws;
    char* after = (char*)d_ws + (size_t)MM * NN * sizeof(PT);
    double* meanA  = (double*)after;
    double* invstd = meanA + (size_t)TT * NN;

    dim3 ggrid(NN / 64, MM / 64);   // (32, 100)
    gemm_psp_kernel<PT><<<ggrid, 256, 0, stream>>>(X, W, PSP);
    stats_kernel<PT><<<TT * (NN / 256), 256, 0, stream>>>(PSP, bias, meanA, invstd);
    recur_kernel<PT><<<BATCH * (NN / 256), 256, 0, stream>>>(
        PSP, bias, meanA, invstd, gamma, decay_v, reset_dec, reset_v, out);
}

extern "C" void kernel_launch(void* const* d_in, const int* in_sizes, int n_in,
                              void* d_out, int out_size, void* d_ws, size_t ws_size,
                              hipStream_t stream) {
    (void)in_sizes; (void)n_in; (void)out_size;
    const float* X          = (const float*)d_in[0];  // [B, DIN, T]
    const float* W          = (const float*)d_in[1];  // [N, DIN]
    const float* bias       = (const float*)d_in[2];  // [N]
    const float* gamma      = (const float*)d_in[3];  // [T, N]
    const float* decay_v    = (const float*)d_in[4];  // [N]
    const float* reset_dec  = (const float*)d_in[5];  // [N]
    const float* reset_v    = (const float*)d_in[6];  // [N]
    float* out = (float*)d_out;

    // fp64 PSP needs ~102 MiB of scratch; fall back to fp32 PSP if ws is small.
    const size_t need_d = (size_t)MM * NN * 8 + (size_t)TT * NN * 16;
    if (ws_size >= need_d)
        launch_all<double>(X, W, bias, gamma, decay_v, reset_dec, reset_v, out, d_ws, stream);
    else
        launch_all<float>(X, W, bias, gamma, decay_v, reset_dec, reset_v, out, d_ws, stream);
}